// Round 16
// baseline (28.936 us; speedup 1.0000x reference)
//
#include <hip/hip_runtime.h>
#include <math.h>

static constexpr int NPT = 98;
static constexpr float CSCALE_HALF = 0.155064240f;  // 0.5 * sqrt(log2(e)/15)

#if __has_builtin(__builtin_amdgcn_exp2f)
#define EXP2F(x) __builtin_amdgcn_exp2f(x)
#else
#define EXP2F(x) exp2f(x)
#endif
#if __has_builtin(__builtin_amdgcn_sqrtf)
#define SQRTF(x) __builtin_amdgcn_sqrtf(x)
#else
#define SQRTF(x) sqrtf(x)
#endif

typedef float v2f __attribute__((ext_vector_type(2)));
typedef float v4a __attribute__((ext_vector_type(4)));               // 16B aligned
typedef float v4fu __attribute__((ext_vector_type(4), aligned(8)));  // 8B aligned
typedef _Float16 h2 __attribute__((ext_vector_type(2)));
typedef _Float16 h4 __attribute__((ext_vector_type(4)));

#if __has_builtin(__builtin_amdgcn_fdot2)
#define FDOT2(a, b, c) __builtin_amdgcn_fdot2((a), (b), (c), false)
#else
#define FDOT2(a, b, c) fmaf((float)(a).x, (float)(b).x, fmaf((float)(a).y, (float)(b).y, (c)))
#endif

#if __has_builtin(__builtin_amdgcn_cvt_pkrtz)
#define PKRTZ(x, y) __builtin_bit_cast(h2, __builtin_amdgcn_cvt_pkrtz((x), (y)))
#else
static __device__ __forceinline__ h2 PKRTZ(float x, float y) {
    h2 r; r.x = (_Float16)x; r.y = (_Float16)y; return r;
}
#endif

// ---- R16: TWO WAVES PER ELEMENT (halve the per-element serial chain) ----
// 256-thr block = 2 elements x 2 waves. Same circulant LDS layout per
// element (h4 {cx,cy,tx,ty} f16):
//  c0:[0,96) dup32  c1:[96,118) c2:[118,140) c3:[140,162) (dup 6 each)
//  c4:[162,182) c5:[182,202) c6:[202,230) c7:[230,254)
// Two-column circulant: lane holds cols {j, j+h}; read at offset t serves
// class t (vs A) and class h-t (vs B). U = sum C(t) + 1/2 C(h).
//
// Work split: co-staged (90 segs/wave, LUT); __syncthreads; then
//   wv0: phaseA t=1..8  + phaseB t=1..3          (28 wdt)
//   wv1: phaseA t=9..16 + mirrors + phaseB t=4,5 (25 wdt)
// landmark distance split 25/24 lanes-of-2-points across the waves.
// Per-wave shfl reduce -> part[eidx][wv] -> one thread per element finishes.
// Rationale: 7 orthogonal nulls left ONE untouched invariant — the
// single-wave per-element dependency chain. This halves it.
// (Two-kernel structure: fused reduction epilogues poison codegen, R10/12/14.)

// Staging LUT: a[6:0] point idx | isg bit7 | dst[15:8] | dup[23:16] (255=none)
struct SLut { unsigned v[192]; };
static constexpr SLut make_slut() {
    SLut L{};
    constexpr int A[8]  = {0, 33, 42, 51, 60, 68, 76, 88};
    constexpr int NS[8] = {32, 8, 8, 8, 7, 7, 11, 9};
    constexpr int BB[8] = {0, 96, 118, 140, 162, 182, 202, 230};
    int s = 0;
    for (int c = 0; c < 8; ++c) {
        int dupn = (c == 0) ? 32 : 6;
        for (int rel = 0; rel < 2 * NS[c]; ++rel, ++s) {
            bool isg = rel >= NS[c];
            int a = A[c] + (isg ? rel - NS[c] : rel);
            int dst = BB[c] + rel;
            int dup = (rel < dupn) ? (BB[c] + 2 * NS[c] + rel) : 255;
            L.v[s] = (unsigned)a | (isg ? 0x80u : 0u)
                   | ((unsigned)dst << 8) | ((unsigned)dup << 16);
        }
    }
    for (; s < 192; ++s) L.v[s] = 0u | (254u << 8) | (255u << 16);
    return L;
}
__constant__ SLut cSLUT = make_slut();

// Phase-B LUT: spOff[7:0] | h[11:8] | TA[14:12] | TB[17:15] | mm bit18
struct BLut { unsigned v[64]; };
static constexpr BLut make_blut() {
    BLut L{};
    constexpr int lo[8]   = {0, 8, 16, 24, 31, 38, 49, 58};
    constexpr int bs[8]   = {96, 118, 140, 162, 182, 202, 230, 202};
    constexpr int hh[8]   = {8, 8, 8, 7, 7, 11, 9, 11};
    constexpr int ta[8]   = {4, 4, 4, 3, 3, 5, 4, 0};
    constexpr int tb[8]   = {3, 3, 3, 3, 3, 5, 4, 0};
    constexpr int mmv[8]  = {1, 1, 1, 1, 1, 1, 1, 0};
    for (int g = 0; g < 8; ++g) {
        int hi = (g < 7) ? lo[g + 1] : 64;
        for (int l = lo[g]; l < hi; ++l) {
            int off = bs[g] + ((g < 7) ? (l - lo[g]) : 0);
            L.v[l] = (unsigned)off | ((unsigned)hh[g] << 8)
                   | ((unsigned)ta[g] << 12) | ((unsigned)tb[g] << 15)
                   | ((unsigned)mmv[g] << 18);
        }
    }
    return L;
}
__constant__ BLut cBLUT = make_blut();

__device__ __forceinline__ float wdt(h4 si, h4 sj) {
    h2 dc = si.xy - sj.xy;                         // v_pk_add_f16
    float d2 = FDOT2(dc, dc, 0.0f);                // v_dot2_f32_f16 (pre-scaled)
    float dt = FDOT2(si.zw, sj.zw, 0.0f);
    return EXP2F(-d2) * dt;
}

__global__ __launch_bounds__(256, 4)   // cap 128 VGPR; natural ~60-80
void lddmm_main(const float* __restrict__ pred, const float* __restrict__ gt,
                float* __restrict__ ws) {
    __shared__ h4 sh[2][256];
    __shared__ float part[2][2];
    const int tid = threadIdx.x;
    const int wave = tid >> 6;      // 0..3
    const int lane = tid & 63;
    __builtin_assume(lane < 64);
    const int eidx = wave >> 1;     // element within block
    const int wv = wave & 1;        // role within element
    const int b = blockIdx.x * 2 + eidx;

    const float* pf = pred + (size_t)b * (2 * NPT);
    const float* gf = gt + (size_t)b * (2 * NPT);
    h4* sw = sh[eidx];

    // eye-corner loads (broadcast; consumed by wv0 lane0 at the end)
    v2f e0 = ((const v2f*)gf)[60];
    v2f e1 = ((const v2f*)gf)[72];

    float diag = 0.0f;    // class-0 partial (this wave's staged segments)
    float accS = 0.0f;    // x1 bucket
    float accA = 0.0f;    // x2 bucket, chain A
    float accB = 0.0f;    // x2 bucket, chain B
    float dsum = 0.0f;

    // ---- staging: 180 segments split across the 2 waves (90 each)
    {   // pass 0: s in [0,128)
        int s = lane + 64 * wv;
        unsigned e = cSLUT.v[s];
        int a = e & 0x7f;
        bool isg = (e & 0x80u) != 0;
        int dst = (int)((e >> 8) & 0xffu);
        int dup = (int)((e >> 16) & 0xffu);
        const float* src = isg ? gf : pf;
        v4fu q = *(const v4fu*)(src + 2 * a);
        v2f c = (q.xy + q.zw) * CSCALE_HALF;
        v2f tau = q.zw - q.xy;
        if (isg) tau = -tau;
        diag = fmaf(tau.x, tau.x, diag);
        diag = fmaf(tau.y, tau.y, diag);
        h2 ch = PKRTZ(c.x, c.y);
        h2 th = PKRTZ(tau.x, tau.y);
        h4 v; v.x = ch.x; v.y = ch.y; v.z = th.x; v.w = th.y;
        sw[dst] = v;
        if (dup != 255) sw[dup] = v;
    }
    {   // pass 1: s in [128,180), 26 lanes per wave
        int s = 128 + 26 * wv + lane;
        if (lane < 26) {
            unsigned e = cSLUT.v[s];
            int a = e & 0x7f;
            bool isg = (e & 0x80u) != 0;
            int dst = (int)((e >> 8) & 0xffu);
            int dup = (int)((e >> 16) & 0xffu);
            const float* src = isg ? gf : pf;
            v4fu q = *(const v4fu*)(src + 2 * a);
            v2f c = (q.xy + q.zw) * CSCALE_HALF;
            v2f tau = q.zw - q.xy;
            if (isg) tau = -tau;
            diag = fmaf(tau.x, tau.x, diag);
            diag = fmaf(tau.y, tau.y, diag);
            h2 ch = PKRTZ(c.x, c.y);
            h2 th = PKRTZ(tau.x, tau.y);
            h4 v; v.x = ch.x; v.y = ch.y; v.z = th.x; v.w = th.y;
            sw[dst] = v;
            if (dup != 255) sw[dup] = v;
        }
    }

    // ---- landmark mean distance, split: wv0 pts 0..49, wv1 pts 50..97
    {
        bool act = wv ? (lane < 24) : (lane < 25);
        if (act) {
            int off = wv ? (100 + 4 * lane) : (4 * lane);
            v4a p4 = *(const v4a*)(pf + off);
            v4a g4 = *(const v4a*)(gf + off);
            v2f d0 = p4.xy - g4.xy;
            v2f d1 = p4.zw - g4.zw;
            dsum = SQRTF(d0.x * d0.x + d0.y * d0.y)
                 + SQRTF(d1.x * d1.x + d1.y * d1.y);
        }
    }

    __syncthreads();   // cross-wave staging visibility (within element)

    // ---- phase A: curve 0 (M=64, h=32), split t-ranges
    {
        h4 sjA = sw[lane];
        h4 sjB = sw[lane + 32];
        if (wv == 0) {
            #pragma unroll
            for (int t = 1; t <= 8; ++t) {
                h4 r = sw[lane + t];
                accA += wdt(r, sjA);
                accB += wdt(r, sjB);
            }
        } else {
            #pragma unroll
            for (int t = 9; t <= 15; ++t) {
                h4 r = sw[lane + t];
                accA += wdt(r, sjA);
                accB += wdt(r, sjB);
            }
            { h4 r = sw[lane + 16]; accA += wdt(r, sjA); }  // t=16: A only
            accS += wdt(sjA, sjB);   // mirror C(32) -> x1
        }
    }

    // ---- phase B: curves c1..c7, LUT-driven, split t-ranges
    {
        unsigned e = cBLUT.v[lane];
        const h4* sp = sw + (e & 0xffu);
        int h = (int)((e >> 8) & 0xfu);
        int TA = (int)((e >> 12) & 7u);
        int TB = (int)((e >> 15) & 7u);
        h4 sjA = sp[0];
        h4 sjB = sp[h];
        if (wv == 0) {
            #pragma unroll
            for (int t = 1; t <= 3; ++t) {   // t<=3 <= TB <= TA for active lanes
                h4 u1 = sp[t];
                h4 u2 = sp[h + t];
                float mA = (t <= TA) ? 1.0f : 0.0f;   // masks only idle lanes
                float mB = (t <= TB) ? 1.0f : 0.0f;
                accA = fmaf(mA, wdt(u1, sjA) + wdt(u2, sjB), accA);
                accB = fmaf(mB, wdt(u1, sjB) + wdt(u2, sjA), accB);
            }
        } else {
            float mm = (e & (1u << 18)) ? 1.0f : 0.0f;
            accA = fmaf(mm, wdt(sjA, sjB), accA);     // mirror = 1/2 C(h) -> x2
            #pragma unroll
            for (int t = 4; t <= 5; ++t) {
                h4 u1 = sp[t];
                h4 u2 = sp[h + t];
                float mA = (t <= TA) ? 1.0f : 0.0f;
                float mB = (t <= TB) ? 1.0f : 0.0f;
                accA = fmaf(mA, wdt(u1, sjA) + wdt(u2, sjB), accA);
                accB = fmaf(mB, wdt(u1, sjB) + wdt(u2, sjA), accB);
            }
        }
    }

    // per-wave combine + shfl reduce -> per-element LDS combine
    float v = 0.8f * dsum + 0.2f * (fmaf(2.0f, accA + accB, diag + accS));
    #pragma unroll
    for (int off = 32; off >= 1; off >>= 1) v += __shfl_xor(v, off, 64);
    if (lane == 0) part[eidx][wv] = v;
    __syncthreads();

    if ((tid & 127) == 0) {   // one thread per element (wv0 lane0)
        float tot = part[eidx][0] + part[eidx][1];
        v2f de = e0 - e1;
        float eye = SQRTF(de.x * de.x + de.y * de.y);
        ws[b] = tot / ((float)NPT * eye);
    }
}

__global__ __launch_bounds__(1024)
void lddmm_reduce(const float* __restrict__ ws, float* __restrict__ out,
                  int n4, float invbatch) {
    __shared__ float sm[1024];
    const int t = threadIdx.x;
    const float4* w4 = (const float4*)ws;
    float s = 0.0f;
    for (int i = t; i < n4; i += 1024) {
        float4 v = w4[i];
        s += (v.x + v.y) + (v.z + v.w);
    }
    sm[t] = s;
    __syncthreads();
    for (int off = 512; off >= 1; off >>= 1) {
        if (t < off) sm[t] += sm[t + off];
        __syncthreads();
    }
    if (t == 0) out[0] = sm[0] * invbatch;
}

extern "C" void kernel_launch(void* const* d_in, const int* in_sizes, int n_in,
                              void* d_out, int out_size, void* d_ws, size_t ws_size,
                              hipStream_t stream) {
    const float* pred = (const float*)d_in[0];
    const float* gt = (const float*)d_in[1];
    float* out = (float*)d_out;
    float* ws = (float*)d_ws;
    const int batch = in_sizes[0] / (2 * NPT);

    const int nblk = batch / 2;   // 2 elements per 256-thr block (2 waves each)
    lddmm_main<<<nblk, 256, 0, stream>>>(pred, gt, ws);
    lddmm_reduce<<<1, 1024, 0, stream>>>(ws, out, batch / 4, 1.0f / (float)batch);
}